// Round 9
// baseline (104.981 us; speedup 1.0000x reference)
//
#include <hip/hip_runtime.h>
#include <hip/hip_bf16.h>
#include <stdint.h>

#define NPB 8192
#define CB 2
#define CC 128
#define HH 4
#define KTOK 4096
#define DH 32
#define NTOK (CB*KTOK)
#define K2C 0.25503402f  /* log2(e)/sqrt(32) */

typedef __attribute__((ext_vector_type(8))) short sh8;
typedef __attribute__((ext_vector_type(4))) float fx4;
typedef __attribute__((ext_vector_type(16))) float fx16;
typedef __attribute__((ext_vector_type(2))) uint32_t ux2;
typedef __attribute__((ext_vector_type(4))) uint32_t ux4;

__device__ inline uint16_t f2bf(float f){
  uint32_t x = __float_as_uint(f);
  return (uint16_t)((x + 0x7FFFu + ((x>>16)&1u)) >> 16);
}
__device__ inline uint32_t pk2(float a, float b){
  return (uint32_t)f2bf(a) | ((uint32_t)f2bf(b) << 16);
}
__device__ inline float fast_exp2(float x){
#if __has_builtin(__builtin_amdgcn_exp2f)
  return __builtin_amdgcn_exp2f(x);
#else
  return exp2f(x);
#endif
}
__device__ inline uint32_t cvtpk1(float a, float b){
  uint32_t u;
  asm("v_cvt_pk_bf16_f32 %0, %1, %2" : "=v"(u) : "v"(a), "v"(b));
  return u;
}
__device__ inline fx4 mfma32(sh8 a, sh8 b, fx4 c){
  return __builtin_amdgcn_mfma_f32_16x16x32_bf16(a, b, c, 0, 0, 0);
}
__device__ inline fx16 mfma32x32(sh8 a, sh8 b, fx16 c){
  return __builtin_amdgcn_mfma_f32_32x32x16_bf16(a, b, c, 0, 0, 0);
}

/* ---------------- K0: copy feats -> out (non-selected rows stay) -------- */
__global__ __launch_bounds__(256) void k_copy(const float4* __restrict__ src,
                                              float4* __restrict__ dst, int n4){
  int i = blockIdx.x*256 + threadIdx.x;
  if (i < n4) dst[i] = src[i];
}

/* ---------------- K1: per-row squared L2 norm as sortable u32 ----------- */
__global__ __launch_bounds__(256) void k_norms(const float* __restrict__ feats,
                                               uint32_t* __restrict__ keys){
  int row  = blockIdx.x*4 + (threadIdx.x>>6);
  int lane = threadIdx.x & 63;
  float2 v = *(const float2*)(feats + row*CC + lane*2);
  float s = v.x*v.x + v.y*v.y;
  for (int m=1; m<64; m<<=1) s += __shfl_xor(s, m);
  if (lane == 0) keys[row] = __float_as_uint(s);  // >=0 -> monotone as uint
}

/* ---------------- K2: exact top-4096 selection per batch ---------------- */
__global__ __launch_bounds__(1024) void k_select(const uint32_t* __restrict__ keys,
                                                 int* __restrict__ sel){
  __shared__ uint32_t ka[NPB];
  __shared__ uint32_t hist[256];
  __shared__ uint32_t sh_prefix, sh_r;
  __shared__ int wsum[17];
  int tid = threadIdx.x, batch = blockIdx.x;
  for (int i = tid; i < NPB; i += 1024) ka[i] = keys[batch*NPB + i];
  if (tid == 0){ sh_prefix = 0u; sh_r = KTOK; }
  __syncthreads();
  for (int pass = 0; pass < 4; ++pass){
    int shift = 24 - 8*pass;
    if (tid < 256) hist[tid] = 0u;
    __syncthreads();
    uint32_t pref = sh_prefix;
    uint32_t r0   = sh_r;
    uint32_t mask = (pass == 0) ? 0u : (0xFFFFFFFFu << (shift + 8));
    for (int e = 0; e < 8; ++e){
      uint32_t k = ka[tid*8 + e];
      if ((k & mask) == pref) atomicAdd(&hist[(k >> shift) & 255], 1u);
    }
    __syncthreads();
    uint32_t h0 = (tid < 256) ? hist[tid] : 0u;
    for (int off = 1; off < 256; off <<= 1){
      uint32_t v = (tid < 256 && tid + off < 256) ? hist[tid + off] : 0u;
      __syncthreads();
      if (tid < 256) hist[tid] += v;
      __syncthreads();
    }
    if (tid < 256){
      uint32_t incl = hist[tid];
      uint32_t Sx   = incl - h0;
      if (Sx < r0 && incl >= r0){
        sh_prefix = pref | ((uint32_t)tid << shift);
        sh_r = r0 - Sx;
      }
    }
    __syncthreads();
  }
  uint32_t T = sh_prefix; int need = (int)sh_r;
  int lgt = 0, leq = 0;
  for (int e = 0; e < 8; ++e){
    uint32_t k = ka[tid*8 + e];
    lgt += (k > T); leq += (k == T);
  }
  int lane = tid & 63, wv = tid >> 6;
  int egt, tgt, eeq;
  {
    __syncthreads();
    int incl = lgt;
    for (int d = 1; d < 64; d <<= 1){ int t = __shfl_up(incl, d); if (lane >= d) incl += t; }
    if (lane == 63) wsum[wv] = incl;
    __syncthreads();
    if (tid == 0){ int run = 0; for (int w = 0; w < 16; ++w){ int t = wsum[w]; wsum[w] = run; run += t; } wsum[16] = run; }
    __syncthreads();
    egt = wsum[wv] + incl - lgt; tgt = wsum[16];
  }
  {
    __syncthreads();
    int incl = leq;
    for (int d = 1; d < 64; d <<= 1){ int t = __shfl_up(incl, d); if (lane >= d) incl += t; }
    if (lane == 63) wsum[wv] = incl;
    __syncthreads();
    if (tid == 0){ int run = 0; for (int w = 0; w < 16; ++w){ int t = wsum[w]; wsum[w] = run; run += t; } }
    __syncthreads();
    eeq = wsum[wv] + incl - leq;
  }
  int chi = tgt, gpos = egt, epos = eeq;
  for (int e = 0; e < 8; ++e){
    int i = tid*8 + e;
    uint32_t k = ka[i];
    if (k > T){ sel[batch*KTOK + (gpos++)] = batch*NPB + i; }
    else if (k == T){ if (epos < need) sel[batch*KTOK + chi + epos] = batch*NPB + i; epos++; }
  }
}

/* ---------------- K3: weights fp32 -> bf16 ------------------------------ */
__global__ __launch_bounds__(256) void k_wconv(const float* __restrict__ wq,
                                               const float* __restrict__ wo,
                                               uint16_t* __restrict__ wqb,
                                               uint16_t* __restrict__ wob){
  int i = blockIdx.x*256 + threadIdx.x;  // 0..65535
  if (i < 3*CC*CC) wqb[i] = f2bf(wq[i]);
  else { int j = i - 3*CC*CC; wob[j] = f2bf(wo[j]); }
}

/* ---------------- K4: gather selected rows to bf16 ---------------------- */
__global__ __launch_bounds__(256) void k_gather(const float* __restrict__ feats,
                                                const int* __restrict__ sel,
                                                uint32_t* __restrict__ xab){
  int t    = blockIdx.x*4 + (threadIdx.x>>6);
  int lane = threadIdx.x & 63;
  int g = sel[t];
  float2 v = *(const float2*)(feats + g*CC + lane*2);
  xab[t*(CC/2) + lane] = pk2(v.x, v.y);
}

/* ---------------- K5: QKV projection GEMM (8192x384x128) ---------------- */
/* Q is pre-scaled by log2(e)/sqrt(Dh) so attention uses exp2 directly.    */
__global__ __launch_bounds__(256) void k_qkv(const uint32_t* __restrict__ xab,
                                             const uint16_t* __restrict__ wqb,
                                             const float* __restrict__ bias,
                                             uint16_t* __restrict__ Qg,
                                             uint16_t* __restrict__ Kg,
                                             uint16_t* __restrict__ Vt){
  int wave = threadIdx.x >> 6, lane = threadIdx.x & 63;
  int l15 = lane & 15, g = lane >> 4;
  int rt = blockIdx.x;               // 512 row tiles
  int ct = blockIdx.y*4 + wave;      // 24 col tiles
  int arow = rt*16 + l15;
  int bcol = ct*16 + l15;
  fx4 acc = {0.f,0.f,0.f,0.f};
  const uint16_t* xb = (const uint16_t*)xab;
#pragma unroll
  for (int kk = 0; kk < 4; ++kk){
    sh8 aF = *(const sh8*)(xb + arow*CC + kk*32 + g*8);
    sh8 bF = *(const sh8*)(wqb + bcol*CC + kk*32 + g*8);
    acc = mfma32(aF, bF, acc);
  }
  int j = bcol;
  float bj = bias[j];
  int tbase = rt*16;
  int b  = tbase >> 12;
  int q0 = (tbase & 4095) + g*4;     // 4 consecutive within-batch slots
  if (j < CC){
    int h = j >> 5, d = j & 31;
    uint16_t* p = Qg + ((b*HH + h)*KTOK + q0)*DH + d;
#pragma unroll
    for (int i = 0; i < 4; ++i) p[i*DH] = f2bf((acc[i] + bj) * K2C);
  } else if (j < 2*CC){
    int jj = j - CC; int h = jj >> 5, d = jj & 31;
    uint16_t* p = Kg + ((b*HH + h)*KTOK + q0)*DH + d;
#pragma unroll
    for (int i = 0; i < 4; ++i) p[i*DH] = f2bf(acc[i] + bj);
  } else {
    int jj = j - 2*CC; int h = jj >> 5, d = jj & 31;
    uint16_t* p = Vt + ((b*HH + h)*DH + d)*KTOK + q0;
    ux2 w; w.x = pk2(acc[0]+bj, acc[1]+bj); w.y = pk2(acc[2]+bj, acc[3]+bj);
    *(ux2*)p = w;
  }
}

/* ---- K6: attention — 32x32 swapped-QK, in-reg P, DIRECT global K/V ----- */
/* Block = 4 waves = one 32q-tile x 4 key-segments (1024 keys each);
   grid 128x8 = 1024 blocks = 4/CU = 16 waves/CU. R8's LDS staging was
   wave-private (no sharing) => pure overhead; K A-frags and V B-frags are
   loaded DIRECTLY global->reg (R5-proven pattern) with 1-deep register
   prefetch (terminal over-reads land in owned ws regions). Loop has ZERO
   LDS traffic and zero barriers. QK^T swapped (A=K,B=Q): D col=q=lane&31,
   row=crow(r,hi) [m101-verified, R8-proven]. No-max softmax, exp2 on
   pre-scaled Q. P -> PV A-frags in-register: 8 cvt_pk + 4 shfl_xor(32).
   Partials combine once in LDS at the end; wave 0 normalizes. */
__global__ __launch_bounds__(256, 4) void k_attn(const uint16_t* __restrict__ Qg,
                                                 const uint16_t* __restrict__ Kg,
                                                 const uint16_t* __restrict__ Vtg,
                                                 uint16_t* __restrict__ O){
  __shared__ float cmb[4][64][16];   /* 16KB partials */
  __shared__ float lwp[4][32];
  __shared__ float ltr[32];
  int tid = threadIdx.x;
  int wv = tid >> 6, lane = tid & 63;
  int l31 = lane & 31, hi = lane >> 5;
  int bh = blockIdx.y;
  int qt = blockIdx.x;                 /* 128 q32-tiles per bh */
  const uint16_t* Qp = Qg  + bh*KTOK*DH;
  const uint16_t* Kp = Kg  + bh*KTOK*DH;
  const uint16_t* Vp = Vtg + bh*DH*KTOK;
  int q = qt*32 + l31;
  sh8 qF0 = *(const sh8*)(Qp + q*DH + hi*8);        /* B: col=q, k=dh 0..15  */
  sh8 qF1 = *(const sh8*)(Qp + q*DH + 16 + hi*8);   /* B: col=q, k=dh 16..31 */

  int key0 = wv*1024;
  const uint16_t* kp = Kp + (key0 + l31)*DH + hi*8; /* A: row=key, k=dh      */
  const uint16_t* vp = Vp + l31*KTOK + key0 + hi*8; /* B: col=dh,  k=key     */

  fx16 acc = {0,0,0,0,0,0,0,0,0,0,0,0,0,0,0,0};
  const fx16 z16 = {0,0,0,0,0,0,0,0,0,0,0,0,0,0,0,0};
  float lsum = 0.f;

  /* prefetch iter 0 */
  sh8 kA0 = *(const sh8*)(kp);
  sh8 kA1 = *(const sh8*)(kp + 16);
  sh8 vB0 = *(const sh8*)(vp);
  sh8 vB1 = *(const sh8*)(vp + 16);

  for (int t = 0; t < 32; ++t){
    kp += 32*DH; vp += 32;
    /* issue next iteration's loads early (final over-read stays in ws) */
    sh8 nk0 = *(const sh8*)(kp);
    sh8 nk1 = *(const sh8*)(kp + 16);
    sh8 nv0 = *(const sh8*)(vp);
    sh8 nv1 = *(const sh8*)(vp + 16);
    fx16 S = mfma32x32(kA0, qF0, z16);
    S = mfma32x32(kA1, qF1, S);
    /* lane holds S for q=l31, keys crow(r,hi)=(r&3)+8*(r>>2)+4*hi */
    float e[16];
#pragma unroll
    for (int r = 0; r < 16; ++r) e[r] = fast_exp2(S[r]);
    float ls = 0.f;
#pragma unroll
    for (int r = 0; r < 16; ++r) ls += e[r];
    lsum += ls;
    uint32_t X0 = cvtpk1(e[0], e[1]),   X1 = cvtpk1(e[2], e[3]);
    uint32_t X2 = cvtpk1(e[4], e[5]),   X3 = cvtpk1(e[6], e[7]);
    uint32_t X4 = cvtpk1(e[8], e[9]),   X5 = cvtpk1(e[10], e[11]);
    uint32_t X6 = cvtpk1(e[12], e[13]), X7 = cvtpk1(e[14], e[15]);
    /* half-exchange (R8-proven): build PV A-frags in-register */
    uint32_t t0 = __shfl_xor(hi ? X0 : X2, 32);
    uint32_t t1 = __shfl_xor(hi ? X1 : X3, 32);
    uint32_t t2 = __shfl_xor(hi ? X4 : X6, 32);
    uint32_t t3 = __shfl_xor(hi ? X5 : X7, 32);
    ux4 w0, w1;
    w0.x = hi ? t0 : X0;  w0.y = hi ? t1 : X1;
    w0.z = hi ? X2 : t0;  w0.w = hi ? X3 : t1;
    w1.x = hi ? t2 : X4;  w1.y = hi ? t3 : X5;
    w1.z = hi ? X6 : t2;  w1.w = hi ? X7 : t3;
    sh8 pa0 = *(sh8*)&w0;   /* A: row=q, k=keys 0..15 of tile  */
    sh8 pa1 = *(sh8*)&w1;   /* A: row=q, k=keys 16..31 of tile */
    acc = mfma32x32(pa0, vB0, acc);
    acc = mfma32x32(pa1, vB1, acc);
    kA0 = nk0; kA1 = nk1; vB0 = nv0; vB1 = nv1;
  }

  /* combine 4 segments */
  lsum += __shfl_xor(lsum, 32);                /* full-segment l for q=l31 */
#pragma unroll
  for (int i = 0; i < 16; i += 4){
    fx4 p = {acc[i], acc[i+1], acc[i+2], acc[i+3]};
    *(fx4*)&cmb[wv][lane][i] = p;
  }
  if (!hi) lwp[wv][l31] = lsum;
  __syncthreads();
  if (wv == 0){
#pragma unroll
    for (int w = 1; w < 4; ++w){
#pragma unroll
      for (int i = 0; i < 16; i += 4){
        fx4 p = *(const fx4*)&cmb[w][lane][i];
        acc[i] += p.x; acc[i+1] += p.y; acc[i+2] += p.z; acc[i+3] += p.w;
      }
    }
    float lt = (lwp[0][l31] + lwp[1][l31]) + (lwp[2][l31] + lwp[3][l31]);
    if (!hi) ltr[l31] = lt;
    fx4 La = *(const fx4*)&ltr[4*hi];
    fx4 Lb = *(const fx4*)&ltr[8+4*hi];
    fx4 Lc = *(const fx4*)&ltr[16+4*hi];
    fx4 Ld = *(const fx4*)&ltr[24+4*hi];
    fx4 Ra = {1.f/La.x, 1.f/La.y, 1.f/La.z, 1.f/La.w};
    fx4 Rb = {1.f/Lb.x, 1.f/Lb.y, 1.f/Lb.z, 1.f/Lb.w};
    fx4 Rc = {1.f/Lc.x, 1.f/Lc.y, 1.f/Lc.z, 1.f/Lc.w};
    fx4 Rd = {1.f/Ld.x, 1.f/Ld.y, 1.f/Ld.z, 1.f/Ld.w};
    int bb = bh >> 2, h = bh & 3;
    uint16_t* op = O + (bb*KTOK + qt*32)*CC + h*DH + l31;
#pragma unroll
    for (int r = 0; r < 16; ++r){
      int qd = (r&3) + 8*(r>>2) + 4*hi;
      float rv = (r<4) ? Ra[r&3] : (r<8) ? Rb[r&3] : (r<12) ? Rc[r&3] : Rd[r&3];
      op[qd*CC] = f2bf(acc[r] * rv);
    }
  }
}

/* ---------------- K7: out-proj + residual + LayerNorm + scatter --------- */
__global__ __launch_bounds__(256) void k_outln(const uint16_t* __restrict__ O,
                                               const uint16_t* __restrict__ wob,
                                               const float* __restrict__ bo,
                                               const float* __restrict__ feats,
                                               const int* __restrict__ sel,
                                               const float* __restrict__ lnw,
                                               const float* __restrict__ lnb,
                                               float* __restrict__ out){
  __shared__ float red[16][4][2];
  int wave = threadIdx.x >> 6, lane = threadIdx.x & 63;
  int l15 = lane & 15, g = lane >> 4;
  int rt = blockIdx.x;
  int arow = rt*16 + l15;
  int jA = wave*32 + l15, jB = jA + 16;
  fx4 accA = {0,0,0,0}, accB = {0,0,0,0};
#pragma unroll
  for (int kk = 0; kk < 4; ++kk){
    sh8 aF = *(const sh8*)(O   + arow*CC + kk*32 + g*8);
    sh8 b0 = *(const sh8*)(wob + jA*CC   + kk*32 + g*8);
    sh8 b1 = *(const sh8*)(wob + jB*CC   + kk*32 + g*8);
    accA = mfma32(aF, b0, accA);
    accB = mfma32(aF, b1, accB);
  }
  float bjA = bo[jA], bjB = bo[jB];
  float hA[4], hB[4]; int gl[4];
#pragma unroll
  for (int i = 0; i < 4; ++i){
    int r = rt*16 + g*4 + i;
    int grow = sel[r];
    gl[i] = grow;
    hA[i] = accA[i] + bjA + feats[grow*CC + jA];
    hB[i] = accB[i] + bjB + feats[grow*CC + jB];
  }
#pragma unroll
  for (int i = 0; i < 4; ++i){
    float s  = hA[i] + hB[i];
    float s2 = hA[i]*hA[i] + hB[i]*hB[i];
    for (int mk = 1; mk < 16; mk <<= 1){ s += __shfl_xor(s, mk); s2 += __shfl_xor(s2, mk); }
    if (l15 == 0){ red[g*4+i][wave][0] = s; red[g*4+i][wave][1] = s2; }
  }
  __syncthreads();
  float w0 = lnw[jA], w1 = lnw[jB], b0v = lnb[jA], b1v = lnb[jB];
#pragma unroll
  for (int i = 0; i < 4; ++i){
    int rl = g*4 + i;
    float tot  = red[rl][0][0] + red[rl][1][0] + red[rl][2][0] + red[rl][3][0];
    float tot2 = red[rl][0][1] + red[rl][1][1] + red[rl][2][1] + red[rl][3][1];
    float mu  = tot  * (1.f/128.f);
    float var = tot2 * (1.f/128.f) - mu*mu;
    float rs = rsqrtf(var + 1e-5f);
    out[gl[i]*CC + jA] = (hA[i]-mu)*rs*w0 + b0v;
    out[gl[i]*CC + jB] = (hB[i]-mu)*rs*w1 + b1v;
  }
}

extern "C" void kernel_launch(void* const* d_in, const int* in_sizes, int n_in,
                              void* d_out, int out_size, void* d_ws, size_t ws_size,
                              hipStream_t stream){
  const float* feats = (const float*)d_in[0];
  /* d_in[1] = batch_idx (int64) — contiguous equal groups, unused */
  const float* wqkv  = (const float*)d_in[2];
  const float* bqkv  = (const float*)d_in[3];
  const float* wout  = (const float*)d_in[4];
  const float* bout  = (const float*)d_in[5];
  const float* lnw   = (const float*)d_in[6];
  const float* lnb   = (const float*)d_in[7];
  float* out = (float*)d_out;
  char* ws = (char*)d_ws;

  uint32_t* keys = (uint32_t*)(ws + 0);        /* 64KB  */
  int*      sel  = (int*)     (ws + 65536);    /* 32KB  */
  uint16_t* wqb  = (uint16_t*)(ws + 98304);    /* 96KB  */
  uint16_t* wob  = (uint16_t*)(ws + 196608);   /* 32KB  */
  uint32_t* xab  = (uint32_t*)(ws + 229376);   /* 2MB   */
  uint16_t* Qg   = (uint16_t*)(ws + 2326528);  /* 2MB   */
  uint16_t* Kg   = (uint16_t*)(ws + 4423680);  /* 2MB   */
  uint16_t* Vt   = (uint16_t*)(ws + 6520832);  /* 2MB   */
  uint16_t* O    = (uint16_t*)(ws + 8617984);  /* 2MB   */

  hipLaunchKernelGGL(k_copy,   dim3(2048),   dim3(256),  0, stream,
                     (const float4*)feats, (float4*)out, (NPB*CB*CC)/4);
  hipLaunchKernelGGL(k_norms,  dim3(4096),   dim3(256),  0, stream, feats, keys);
  hipLaunchKernelGGL(k_select, dim3(2),      dim3(1024), 0, stream, keys, sel);
  hipLaunchKernelGGL(k_wconv,  dim3(256),    dim3(256),  0, stream, wqkv, wout, wqb, wob);
  hipLaunchKernelGGL(k_gather, dim3(2048),   dim3(256),  0, stream, feats, sel, xab);
  hipLaunchKernelGGL(k_qkv,    dim3(512,6),  dim3(256),  0, stream, xab, wqb, bqkv, Qg, Kg, Vt);
  hipLaunchKernelGGL(k_attn,   dim3(128,8),  dim3(256),  0, stream, Qg, Kg, Vt, O);
  hipLaunchKernelGGL(k_outln,  dim3(512),    dim3(256),  0, stream, O, wob, bout, feats, sel, lnw, lnb, out);
}

// Round 10
// 94.730 us; speedup vs baseline: 1.1082x; 1.1082x over previous
//
#include <hip/hip_runtime.h>
#include <hip/hip_bf16.h>
#include <stdint.h>

#define NPB 8192
#define CB 2
#define CC 128
#define HH 4
#define KTOK 4096
#define DH 32
#define NTOK (CB*KTOK)
#define K2C 0.25503402f  /* log2(e)/sqrt(32) */

typedef __attribute__((ext_vector_type(8))) short sh8;
typedef __attribute__((ext_vector_type(4))) float fx4;
typedef __attribute__((ext_vector_type(16))) float fx16;
typedef __attribute__((ext_vector_type(2))) uint32_t ux2;
typedef __attribute__((ext_vector_type(4))) uint32_t ux4;

__device__ inline uint16_t f2bf(float f){
  uint32_t x = __float_as_uint(f);
  return (uint16_t)((x + 0x7FFFu + ((x>>16)&1u)) >> 16);
}
__device__ inline uint32_t pk2(float a, float b){
  return (uint32_t)f2bf(a) | ((uint32_t)f2bf(b) << 16);
}
__device__ inline float fast_exp2(float x){
#if __has_builtin(__builtin_amdgcn_exp2f)
  return __builtin_amdgcn_exp2f(x);
#else
  return exp2f(x);
#endif
}
__device__ inline uint32_t cvtpk1(float a, float b){
  uint32_t u;
  asm("v_cvt_pk_bf16_f32 %0, %1, %2" : "=v"(u) : "v"(a), "v"(b));
  return u;
}
__device__ inline fx4 mfma32(sh8 a, sh8 b, fx4 c){
  return __builtin_amdgcn_mfma_f32_16x16x32_bf16(a, b, c, 0, 0, 0);
}
__device__ inline fx16 mfma32x32(sh8 a, sh8 b, fx16 c){
  return __builtin_amdgcn_mfma_f32_32x32x16_bf16(a, b, c, 0, 0, 0);
}
__device__ inline void gload_lds(const uint16_t* g, uint16_t* l){
  __builtin_amdgcn_global_load_lds(
      (const __attribute__((address_space(1))) uint32_t*)g,
      (__attribute__((address_space(3))) uint32_t*)l,
      16, 0, 0);
}

/* ---------------- K0: copy feats -> out (non-selected rows stay) -------- */
__global__ __launch_bounds__(256) void k_copy(const float4* __restrict__ src,
                                              float4* __restrict__ dst, int n4){
  int i = blockIdx.x*256 + threadIdx.x;
  if (i < n4) dst[i] = src[i];
}

/* ---------------- K1: per-row squared L2 norm as sortable u32 ----------- */
__global__ __launch_bounds__(256) void k_norms(const float* __restrict__ feats,
                                               uint32_t* __restrict__ keys){
  int row  = blockIdx.x*4 + (threadIdx.x>>6);
  int lane = threadIdx.x & 63;
  float2 v = *(const float2*)(feats + row*CC + lane*2);
  float s = v.x*v.x + v.y*v.y;
  for (int m=1; m<64; m<<=1) s += __shfl_xor(s, m);
  if (lane == 0) keys[row] = __float_as_uint(s);  // >=0 -> monotone as uint
}

/* ---------------- K2: exact top-4096 selection per batch ---------------- */
/* Per-wave privatized histograms (stride 257 -> hot bin spread over 16
   banks, ~16x less atomic serialization on concentrated keys), then a
   256-thread cross-wave reduce; semantics identical to the R8 version. */
__global__ __launch_bounds__(1024) void k_select(const uint32_t* __restrict__ keys,
                                                 int* __restrict__ sel){
  __shared__ uint32_t ka[NPB];
  __shared__ uint32_t hist[16*257];
  __shared__ uint32_t comb[256];
  __shared__ uint32_t sh_prefix, sh_r;
  __shared__ int wsum[17];
  int tid = threadIdx.x, batch = blockIdx.x;
  int wv16 = tid >> 6;
  for (int i = tid; i < NPB; i += 1024) ka[i] = keys[batch*NPB + i];
  if (tid == 0){ sh_prefix = 0u; sh_r = KTOK; }
  __syncthreads();
  for (int pass = 0; pass < 4; ++pass){
    int shift = 24 - 8*pass;
    for (int i = tid; i < 16*257; i += 1024) hist[i] = 0u;
    __syncthreads();
    uint32_t pref = sh_prefix;
    uint32_t r0   = sh_r;
    uint32_t mask = (pass == 0) ? 0u : (0xFFFFFFFFu << (shift + 8));
    uint32_t* myh = &hist[wv16*257];
    for (int e = 0; e < 8; ++e){
      uint32_t k = ka[tid*8 + e];
      if ((k & mask) == pref) atomicAdd(&myh[(k >> shift) & 255], 1u);
    }
    __syncthreads();
    uint32_t h0 = 0;
    if (tid < 256){
      for (int w = 0; w < 16; ++w) h0 += hist[w*257 + tid];
      comb[tid] = h0;
    }
    __syncthreads();
    /* parallel inclusive suffix scan of comb (in place) */
    for (int off = 1; off < 256; off <<= 1){
      uint32_t v = (tid < 256 && tid + off < 256) ? comb[tid + off] : 0u;
      __syncthreads();
      if (tid < 256) comb[tid] += v;
      __syncthreads();
    }
    if (tid < 256){
      uint32_t incl = comb[tid];      /* keys with bin >= tid (in prefix) */
      uint32_t Sx   = incl - h0;      /* strictly-greater bins            */
      if (Sx < r0 && incl >= r0){
        sh_prefix = pref | ((uint32_t)tid << shift);
        sh_r = r0 - Sx;
      }
    }
    __syncthreads();
  }
  uint32_t T = sh_prefix; int need = (int)sh_r;
  int lgt = 0, leq = 0;
  for (int e = 0; e < 8; ++e){
    uint32_t k = ka[tid*8 + e];
    lgt += (k > T); leq += (k == T);
  }
  int lane = tid & 63, wv = tid >> 6;
  int egt, tgt, eeq;
  {
    __syncthreads();
    int incl = lgt;
    for (int d = 1; d < 64; d <<= 1){ int t = __shfl_up(incl, d); if (lane >= d) incl += t; }
    if (lane == 63) wsum[wv] = incl;
    __syncthreads();
    if (tid == 0){ int run = 0; for (int w = 0; w < 16; ++w){ int t = wsum[w]; wsum[w] = run; run += t; } wsum[16] = run; }
    __syncthreads();
    egt = wsum[wv] + incl - lgt; tgt = wsum[16];
  }
  {
    __syncthreads();
    int incl = leq;
    for (int d = 1; d < 64; d <<= 1){ int t = __shfl_up(incl, d); if (lane >= d) incl += t; }
    if (lane == 63) wsum[wv] = incl;
    __syncthreads();
    if (tid == 0){ int run = 0; for (int w = 0; w < 16; ++w){ int t = wsum[w]; wsum[w] = run; run += t; } }
    __syncthreads();
    eeq = wsum[wv] + incl - leq;
  }
  int chi = tgt, gpos = egt, epos = eeq;
  for (int e = 0; e < 8; ++e){
    int i = tid*8 + e;
    uint32_t k = ka[i];
    if (k > T){ sel[batch*KTOK + (gpos++)] = batch*NPB + i; }
    else if (k == T){ if (epos < need) sel[batch*KTOK + chi + epos] = batch*NPB + i; epos++; }
  }
}

/* ---------------- K3: weights fp32 -> bf16 ------------------------------ */
__global__ __launch_bounds__(256) void k_wconv(const float* __restrict__ wq,
                                               const float* __restrict__ wo,
                                               uint16_t* __restrict__ wqb,
                                               uint16_t* __restrict__ wob){
  int i = blockIdx.x*256 + threadIdx.x;  // 0..65535
  if (i < 3*CC*CC) wqb[i] = f2bf(wq[i]);
  else { int j = i - 3*CC*CC; wob[j] = f2bf(wo[j]); }
}

/* ---------------- K4: gather selected rows to bf16 ---------------------- */
__global__ __launch_bounds__(256) void k_gather(const float* __restrict__ feats,
                                                const int* __restrict__ sel,
                                                uint32_t* __restrict__ xab){
  int t    = blockIdx.x*4 + (threadIdx.x>>6);
  int lane = threadIdx.x & 63;
  int g = sel[t];
  float2 v = *(const float2*)(feats + g*CC + lane*2);
  xab[t*(CC/2) + lane] = pk2(v.x, v.y);
}

/* ---------------- K5: QKV projection GEMM (8192x384x128) ---------------- */
/* Q is pre-scaled by log2(e)/sqrt(Dh) so attention uses exp2 directly.    */
__global__ __launch_bounds__(256) void k_qkv(const uint32_t* __restrict__ xab,
                                             const uint16_t* __restrict__ wqb,
                                             const float* __restrict__ bias,
                                             uint16_t* __restrict__ Qg,
                                             uint16_t* __restrict__ Kg,
                                             uint16_t* __restrict__ Vt){
  int wave = threadIdx.x >> 6, lane = threadIdx.x & 63;
  int l15 = lane & 15, g = lane >> 4;
  int rt = blockIdx.x;               // 512 row tiles
  int ct = blockIdx.y*4 + wave;      // 24 col tiles
  int arow = rt*16 + l15;
  int bcol = ct*16 + l15;
  fx4 acc = {0.f,0.f,0.f,0.f};
  const uint16_t* xb = (const uint16_t*)xab;
#pragma unroll
  for (int kk = 0; kk < 4; ++kk){
    sh8 aF = *(const sh8*)(xb + arow*CC + kk*32 + g*8);
    sh8 bF = *(const sh8*)(wqb + bcol*CC + kk*32 + g*8);
    acc = mfma32(aF, bF, acc);
  }
  int j = bcol;
  float bj = bias[j];
  int tbase = rt*16;
  int b  = tbase >> 12;
  int q0 = (tbase & 4095) + g*4;     // 4 consecutive within-batch slots
  if (j < CC){
    int h = j >> 5, d = j & 31;
    uint16_t* p = Qg + ((b*HH + h)*KTOK + q0)*DH + d;
#pragma unroll
    for (int i = 0; i < 4; ++i) p[i*DH] = f2bf((acc[i] + bj) * K2C);
  } else if (j < 2*CC){
    int jj = j - CC; int h = jj >> 5, d = jj & 31;
    uint16_t* p = Kg + ((b*HH + h)*KTOK + q0)*DH + d;
#pragma unroll
    for (int i = 0; i < 4; ++i) p[i*DH] = f2bf(acc[i] + bj);
  } else {
    int jj = j - 2*CC; int h = jj >> 5, d = jj & 31;
    uint16_t* p = Vt + ((b*HH + h)*DH + d)*KTOK + q0;
    ux2 w; w.x = pk2(acc[0]+bj, acc[1]+bj); w.y = pk2(acc[2]+bj, acc[3]+bj);
    *(ux2*)p = w;
  }
}

/* ---- K6: attention — R8 structure, CONFLICT-FREE swizzle --------------- */
/* Identical to R8 (proven 46.8us) except the LDS swizzle: bank index is
   ((row&1)<<4)|(slot<<2)|sub, so the XOR must use row bits 1-2:
   slot' = slot ^ ((row>>1)&3). Each consecutive 8-lane b128 read group
   then covers all 32 banks exactly once (enumerated) -> conflict-free.
   Source permute and read permute changed together (G21). */
__global__ __launch_bounds__(256, 4) void k_attn(const uint16_t* __restrict__ Qg,
                                                 const uint16_t* __restrict__ Kg,
                                                 const uint16_t* __restrict__ Vtg,
                                                 uint16_t* __restrict__ O){
  __shared__ __align__(16) char lds[32768];
  int tid = threadIdx.x;
  int wv = tid >> 6, lane = tid & 63;
  int l31 = lane & 31, hi = lane >> 5;
  int bh = blockIdx.y;
  int qt = blockIdx.x;                 /* 128 q32-tiles per bh */
  const uint16_t* Qp = Qg  + bh*KTOK*DH;
  const uint16_t* Kp = Kg  + bh*KTOK*DH;
  const uint16_t* Vp = Vtg + bh*DH*KTOK;
  int q = qt*32 + l31;
  sh8 qF0 = *(const sh8*)(Qp + q*DH + hi*8);        /* B: col=q, k=dh 0..15  */
  sh8 qF1 = *(const sh8*)(Qp + q*DH + 16 + hi*8);   /* B: col=q, k=dh 16..31 */

  uint16_t* st = (uint16_t*)lds + wv*4096;  /* 8KB/wave: [2 buf][K 1024 | V 1024] elems */
  int key0 = wv*1024;
  int r16 = lane >> 2;
  int sx  = ((lane & 3) ^ ((r16 >> 1) & 3)) * 8;   /* pre-swizzled source slot */

  /* prologue: stage tile 0 -> buf0 */
  {
    const uint16_t* kg = Kp + key0*DH;
    const uint16_t* vg = Vp + key0;
    gload_lds(kg + r16*DH + sx,        st + 0);
    gload_lds(kg + (16+r16)*DH + sx,   st + 512);
    gload_lds(vg + r16*KTOK + sx,      st + 1024);
    gload_lds(vg + (16+r16)*KTOK + sx, st + 1536);
  }
  asm volatile("s_waitcnt vmcnt(0)" ::: "memory");

  fx16 acc = {0,0,0,0,0,0,0,0,0,0,0,0,0,0,0,0};
  const fx16 z16 = {0,0,0,0,0,0,0,0,0,0,0,0,0,0,0,0};
  float lsum = 0.f;
  int swz = (l31 >> 1) & 3;
  int koff0 = l31*32 + ((hi     ^ swz)*8);
  int koff1 = l31*32 + (((hi+2) ^ swz)*8);
  int voff0 = l31*32 + ((hi     ^ swz)*8);
  int voff1 = l31*32 + (((hi+2) ^ swz)*8);

  for (int t = 0; t < 32; ++t){
    int b = t & 1;
    if (t < 31){
      const uint16_t* kg = Kp + (key0 + (t+1)*32)*DH;
      const uint16_t* vg = Vp + key0 + (t+1)*32;
      uint16_t* d = st + (b^1)*2048;
      gload_lds(kg + r16*DH + sx,        d + 0);
      gload_lds(kg + (16+r16)*DH + sx,   d + 512);
      gload_lds(vg + r16*KTOK + sx,      d + 1024);
      gload_lds(vg + (16+r16)*KTOK + sx, d + 1536);
    }
    const uint16_t* bK = st + b*2048;
    const uint16_t* bV = st + b*2048 + 1024;
    sh8 kA0 = *(const sh8*)(bK + koff0);
    sh8 kA1 = *(const sh8*)(bK + koff1);
    fx16 S = mfma32x32(kA0, qF0, z16);
    S = mfma32x32(kA1, qF1, S);
    /* lane holds S for q=l31, keys crow(r,hi)=(r&3)+8*(r>>2)+4*hi */
    float e[16];
#pragma unroll
    for (int r = 0; r < 16; ++r) e[r] = fast_exp2(S[r]);
    float ls = 0.f;
#pragma unroll
    for (int r = 0; r < 16; ++r) ls += e[r];
    lsum += ls;
    uint32_t X0 = cvtpk1(e[0], e[1]),   X1 = cvtpk1(e[2], e[3]);
    uint32_t X2 = cvtpk1(e[4], e[5]),   X3 = cvtpk1(e[6], e[7]);
    uint32_t X4 = cvtpk1(e[8], e[9]),   X5 = cvtpk1(e[10], e[11]);
    uint32_t X6 = cvtpk1(e[12], e[13]), X7 = cvtpk1(e[14], e[15]);
    /* half-exchange: build PV A-frags in-register (R8-proven) */
    uint32_t t0 = __shfl_xor(hi ? X0 : X2, 32);
    uint32_t t1 = __shfl_xor(hi ? X1 : X3, 32);
    uint32_t t2 = __shfl_xor(hi ? X4 : X6, 32);
    uint32_t t3 = __shfl_xor(hi ? X5 : X7, 32);
    ux4 w0, w1;
    w0.x = hi ? t0 : X0;  w0.y = hi ? t1 : X1;
    w0.z = hi ? X2 : t0;  w0.w = hi ? X3 : t1;
    w1.x = hi ? t2 : X4;  w1.y = hi ? t3 : X5;
    w1.z = hi ? X6 : t2;  w1.w = hi ? X7 : t3;
    sh8 pa0 = *(sh8*)&w0;   /* A: row=q, k=keys 0..15 of tile  */
    sh8 pa1 = *(sh8*)&w1;   /* A: row=q, k=keys 16..31 of tile */
    sh8 vB0 = *(const sh8*)(bV + voff0);   /* B: col=dh, k=keys 0..15  */
    sh8 vB1 = *(const sh8*)(bV + voff1);   /* B: col=dh, k=keys 16..31 */
    acc = mfma32x32(pa0, vB0, acc);
    acc = mfma32x32(pa1, vB1, acc);
    asm volatile("s_waitcnt vmcnt(0)" ::: "memory");
  }

  /* combine 4 segments; reuse lds (all waves past their loops after barrier) */
  __syncthreads();
  float* cmb = (float*)lds;                    /* [4][64][16] f32 = 16KB */
  float* lwp = (float*)(lds + 16384);          /* [4][32] f32            */
  float* ltr = (float*)(lds + 16384 + 512);    /* [32] f32               */
  lsum += __shfl_xor(lsum, 32);                /* full-segment l for q=l31 */
#pragma unroll
  for (int i = 0; i < 16; i += 4){
    fx4 p = {acc[i], acc[i+1], acc[i+2], acc[i+3]};
    *(fx4*)&cmb[(wv*64 + lane)*16 + i] = p;
  }
  if (!hi) lwp[wv*32 + l31] = lsum;
  __syncthreads();
  if (wv == 0){
#pragma unroll
    for (int w = 1; w < 4; ++w){
#pragma unroll
      for (int i = 0; i < 16; i += 4){
        fx4 p = *(const fx4*)&cmb[(w*64 + lane)*16 + i];
        acc[i] += p.x; acc[i+1] += p.y; acc[i+2] += p.z; acc[i+3] += p.w;
      }
    }
    float lt = (lwp[l31] + lwp[32+l31]) + (lwp[64+l31] + lwp[96+l31]);
    if (!hi) ltr[l31] = lt;
    fx4 La = *(const fx4*)&ltr[4*hi];
    fx4 Lb = *(const fx4*)&ltr[8+4*hi];
    fx4 Lc = *(const fx4*)&ltr[16+4*hi];
    fx4 Ld = *(const fx4*)&ltr[24+4*hi];
    fx4 Ra = {1.f/La.x, 1.f/La.y, 1.f/La.z, 1.f/La.w};
    fx4 Rb = {1.f/Lb.x, 1.f/Lb.y, 1.f/Lb.z, 1.f/Lb.w};
    fx4 Rc = {1.f/Lc.x, 1.f/Lc.y, 1.f/Lc.z, 1.f/Lc.w};
    fx4 Rd = {1.f/Ld.x, 1.f/Ld.y, 1.f/Ld.z, 1.f/Ld.w};
    int bb = bh >> 2, h = bh & 3;
    uint16_t* op = O + (bb*KTOK + qt*32)*CC + h*DH + l31;
#pragma unroll
    for (int r = 0; r < 16; ++r){
      int qd = (r&3) + 8*(r>>2) + 4*hi;
      float rv = (r<4) ? Ra[r&3] : (r<8) ? Rb[r&3] : (r<12) ? Rc[r&3] : Rd[r&3];
      op[qd*CC] = f2bf(acc[r] * rv);
    }
  }
}

/* ---------------- K7: out-proj + residual + LayerNorm + scatter --------- */
__global__ __launch_bounds__(256) void k_outln(const uint16_t* __restrict__ O,
                                               const uint16_t* __restrict__ wob,
                                               const float* __restrict__ bo,
                                               const float* __restrict__ feats,
                                               const int* __restrict__ sel,
                                               const float* __restrict__ lnw,
                                               const float* __restrict__ lnb,
                                               float* __restrict__ out){
  __shared__ float red[16][4][2];
  int wave = threadIdx.x >> 6, lane = threadIdx.x & 63;
  int l15 = lane & 15, g = lane >> 4;
  int rt = blockIdx.x;
  int arow = rt*16 + l15;
  int jA = wave*32 + l15, jB = jA + 16;
  fx4 accA = {0,0,0,0}, accB = {0,0,0,0};
#pragma unroll
  for (int kk = 0; kk < 4; ++kk){
    sh8 aF = *(const sh8*)(O   + arow*CC + kk*32 + g*8);
    sh8 b0 = *(const sh8*)(wob + jA*CC   + kk*32 + g*8);
    sh8 b1 = *(const sh8*)(wob + jB*CC   + kk*32 + g*8);
    accA = mfma32(aF, b0, accA);
    accB = mfma32(aF, b1, accB);
  }
  float bjA = bo[jA], bjB = bo[jB];
  float hA[4], hB[4]; int gl[4];
#pragma unroll
  for (int i = 0; i < 4; ++i){
    int r = rt*16 + g*4 + i;
    int grow = sel[r];
    gl[i] = grow;
    hA[i] = accA[i] + bjA + feats[grow*CC + jA];
    hB[i] = accB[i] + bjB + feats[grow*CC + jB];
  }
#pragma unroll
  for (int i = 0; i < 4; ++i){
    float s  = hA[i] + hB[i];
    float s2 = hA[i]*hA[i] + hB[i]*hB[i];
    for (int mk = 1; mk < 16; mk <<= 1){ s += __shfl_xor(s, mk); s2 += __shfl_xor(s2, mk); }
    if (l15 == 0){ red[g*4+i][wave][0] = s; red[g*4+i][wave][1] = s2; }
  }
  __syncthreads();
  float w0 = lnw[jA], w1 = lnw[jB], b0v = lnb[jA], b1v = lnb[jB];
#pragma unroll
  for (int i = 0; i < 4; ++i){
    int rl = g*4 + i;
    float tot  = red[rl][0][0] + red[rl][1][0] + red[rl][2][0] + red[rl][3][0];
    float tot2 = red[rl][0][1] + red[rl][1][1] + red[rl][2][1] + red[rl][3][1];
    float mu  = tot  * (1.f/128.f);
    float var = tot2 * (1.f/128.f) - mu*mu;
    float rs = rsqrtf(var + 1e-5f);
    out[gl[i]*CC + jA] = (hA[i]-mu)*rs*w0 + b0v;
    out[gl[i]*CC + jB] = (hB[i]-mu)*rs*w1 + b1v;
  }
}

extern "C" void kernel_launch(void* const* d_in, const int* in_sizes, int n_in,
                              void* d_out, int out_size, void* d_ws, size_t ws_size,
                              hipStream_t stream){
  const float* feats = (const float*)d_in[0];
  /* d_in[1] = batch_idx (int64) — contiguous equal groups, unused */
  const float* wqkv  = (const float*)d_in[2];
  const float* bqkv  = (const float*)d_in[3];
  const float* wout  = (const float*)d_in[4];
  const float* bout  = (const float*)d_in[5];
  const float* lnw   = (const float*)d_in[6];
  const float* lnb   = (const float*)d_in[7];
  float* out = (float*)d_out;
  char* ws = (char*)d_ws;

  uint32_t* keys = (uint32_t*)(ws + 0);        /* 64KB  */
  int*      sel  = (int*)     (ws + 65536);    /* 32KB  */
  uint16_t* wqb  = (uint16_t*)(ws + 98304);    /* 96KB  */
  uint16_t* wob  = (uint16_t*)(ws + 196608);   /* 32KB  */
  uint32_t* xab  = (uint32_t*)(ws + 229376);   /* 2MB   */
  uint16_t* Qg   = (uint16_t*)(ws + 2326528);  /* 2MB   */
  uint16_t* Kg   = (uint16_t*)(ws + 4423680);  /* 2MB   */
  uint16_t* Vt   = (uint16_t*)(ws + 6520832);  /* 2MB   */
  uint16_t* O    = (uint16_t*)(ws + 8617984);  /* 2MB   */

  hipLaunchKernelGGL(k_copy,   dim3(2048),   dim3(256),  0, stream,
                     (const float4*)feats, (float4*)out, (NPB*CB*CC)/4);
  hipLaunchKernelGGL(k_norms,  dim3(4096),   dim3(256),  0, stream, feats, keys);
  hipLaunchKernelGGL(k_select, dim3(2),      dim3(1024), 0, stream, keys, sel);
  hipLaunchKernelGGL(k_wconv,  dim3(256),    dim3(256),  0, stream, wqkv, wout, wqb, wob);
  hipLaunchKernelGGL(k_gather, dim3(2048),   dim3(256),  0, stream, feats, sel, xab);
  hipLaunchKernelGGL(k_qkv,    dim3(512,6),  dim3(256),  0, stream, xab, wqb, bqkv, Qg, Kg, Vt);
  hipLaunchKernelGGL(k_attn,   dim3(128,8),  dim3(256),  0, stream, Qg, Kg, Vt, O);
  hipLaunchKernelGGL(k_outln,  dim3(512),    dim3(256),  0, stream, O, wob, bout, feats, sel, lnw, lnb, out);
}